// Round 1
// baseline (1491.487 us; speedup 1.0000x reference)
//
#include <hip/hip_runtime.h>
#include <cstdint>
#include <cstddef>

#define D 1024
#define BATCH 16384
#define NLAYERS 18
#define RR 32

typedef __attribute__((ext_vector_type(8))) __bf16 bf16x8;
typedef __attribute__((ext_vector_type(4))) float f32x4;
typedef __attribute__((address_space(3))) void lds_void_t;
typedef __attribute__((address_space(1))) void gmem_void_t;

__device__ __forceinline__ unsigned short f2bf(float f) {
    unsigned int b = __builtin_bit_cast(unsigned int, f);
    b += 0x7fffu + ((b >> 16) & 1u);
    return (unsigned short)(b >> 16);
}

// ---------------------------------------------------------------------------
// W_eff[li][o][i] = (q/15*2-1)*scale[o][i/16] + 4 * sum_r lb[o][r]*la[r][i]
// one thread per 8 consecutive i. Stored bf16.
// ---------------------------------------------------------------------------
__global__ __launch_bounds__(256) void prep_weights(
    const int* __restrict__ q, const float* __restrict__ scales,
    const float* __restrict__ la, const float* __restrict__ lb,
    unsigned short* __restrict__ weff) {
    const int tid = blockIdx.x * 256 + threadIdx.x;   // < NLAYERS*D*128
    const int i8 = tid & 127;
    const int row = tid >> 7;                         // li*D + o
    const int li = row >> 10;
    const int i0 = i8 << 3;
    const float s = scales[(size_t)row * (D / 16) + (i0 >> 4)];
    const float* lap = la + (size_t)li * RR * D + i0;
    const float* lbp = lb + (size_t)row * RR;
    float acc[8] = {0.f, 0.f, 0.f, 0.f, 0.f, 0.f, 0.f, 0.f};
#pragma unroll 4
    for (int r = 0; r < RR; ++r) {
        const float bv = lbp[r];
        const float4* lar = (const float4*)(lap + (size_t)r * D);
        float4 l0 = lar[0], l1 = lar[1];
        acc[0] += bv * l0.x; acc[1] += bv * l0.y; acc[2] += bv * l0.z; acc[3] += bv * l0.w;
        acc[4] += bv * l1.x; acc[5] += bv * l1.y; acc[6] += bv * l1.z; acc[7] += bv * l1.w;
    }
    const int* qp = q + (size_t)row * D + i0;
    int4 qv0 = ((const int4*)qp)[0];
    int4 qv1 = ((const int4*)qp)[1];
    int qa[8] = {qv0.x, qv0.y, qv0.z, qv0.w, qv1.x, qv1.y, qv1.z, qv1.w};
    union { unsigned short us[8]; int4 v; } u;
    const float c = 2.0f / 15.0f;
#pragma unroll
    for (int j = 0; j < 8; ++j) {
        float w = ((float)qa[j] * c - 1.0f) * s + 4.0f * acc[j];
        u.us[j] = f2bf(w);
    }
    *(int4*)(weff + (size_t)row * D + i0) = u.v;
}

// h = x (f32); xb = bf16(x)
__global__ __launch_bounds__(256) void init_h(const float* __restrict__ x,
                                              float* __restrict__ h,
                                              unsigned short* __restrict__ xb) {
    const size_t i = (size_t)blockIdx.x * 256 + threadIdx.x;  // per 4 elems
    float4 v = ((const float4*)x)[i];
    ((float4*)h)[i] = v;
    ushort4 u;
    u.x = f2bf(v.x); u.y = f2bf(v.y); u.z = f2bf(v.z); u.w = f2bf(v.w);
    ((ushort4*)xb)[i] = u;
}

// ---------------------------------------------------------------------------
// C[m][n] = sum_k xb[m][k] * w[n][k] + bias[n]   (NT layout, bf16 MFMA)
// 128x128 tile, BK=64, 4 waves (2x2), 4x4 16x16x32 frags per wave.
// global_load_lds(16B) staging, linear LDS dest + pre-swizzled source,
// XOR-swizzled ds_read_b128 (byte ^= (row&7)<<4)  -> 2-way conflicts (free).
// mode 0: outb = bf16(relu(v));  mode 1: hbuf += v;  mode 2: outf = hbuf + v.
// ---------------------------------------------------------------------------
__global__ __launch_bounds__(256) void gemm_fused(
    const unsigned short* __restrict__ xb, const unsigned short* __restrict__ w,
    const float* __restrict__ bias,
    unsigned short* __restrict__ outb, float* __restrict__ hbuf,
    float* __restrict__ outf, int mode) {
    __shared__ __align__(16) char smem[32768];   // A: [0,16K), B: [16K,32K)
    const int tid = threadIdx.x;
    const int wid = tid >> 6, lane = tid & 63;
    const int m0 = blockIdx.y << 7;
    const int n0 = blockIdx.x << 7;

    f32x4 acc[4][4];
#pragma unroll
    for (int i = 0; i < 4; ++i)
#pragma unroll
        for (int j = 0; j < 4; ++j) acc[i][j] = 0.0f;

    const int wrow = (wid >> 1) << 6;   // wave row offset (A): 0/64
    const int wcol = (wid & 1) << 6;    // wave col offset (B): 0/64
    const int l15 = lane & 15;
    const int kgrp = lane >> 4;

    for (int ks = 0; ks < 16; ++ks) {
        __syncthreads();
        const int k0 = ks << 6;
#pragma unroll
        for (int i = 0; i < 4; ++i) {
            const int idx = i * 256 + tid;
            const int row = idx >> 3;                 // 0..127
            const int c8 = (idx & 7) ^ (row & 7);     // inverse-swizzled source chunk
            const unsigned short* ga = xb + (size_t)(m0 + row) * D + k0 + (c8 << 3);
            const unsigned short* gb = w  + (size_t)(n0 + row) * D + k0 + (c8 << 3);
            char* lA = smem + ((i * 256 + (wid << 6)) << 4);  // wave-uniform base
            char* lB = lA + 16384;
            __builtin_amdgcn_global_load_lds((const gmem_void_t*)ga, (lds_void_t*)lA, 16, 0, 0);
            __builtin_amdgcn_global_load_lds((const gmem_void_t*)gb, (lds_void_t*)lB, 16, 0, 0);
        }
        __syncthreads();
#pragma unroll
        for (int kk = 0; kk < 2; ++kk) {
            const int kb = (kk << 6) + (kgrp << 4);   // k byte offset within row
            bf16x8 a[4], b[4];
#pragma unroll
            for (int f = 0; f < 4; ++f) {
                const int rowa = wrow + (f << 4) + l15;
                const int offa = ((rowa << 7) + kb) ^ ((rowa & 7) << 4);
                a[f] = *(const bf16x8*)(smem + offa);
                const int rowb = wcol + (f << 4) + l15;
                const int offb = ((rowb << 7) + kb) ^ ((rowb & 7) << 4);
                b[f] = *(const bf16x8*)(smem + 16384 + offb);
            }
#pragma unroll
            for (int mi = 0; mi < 4; ++mi)
#pragma unroll
                for (int ni = 0; ni < 4; ++ni)
                    acc[mi][ni] = __builtin_amdgcn_mfma_f32_16x16x32_bf16(
                        a[mi], b[ni], acc[mi][ni], 0, 0, 0);
        }
    }

    // epilogue: C/D layout col = lane&15, row = (lane>>4)*4 + r  [m89-verified]
    const int crow = kgrp << 2;
    float bv[4];
#pragma unroll
    for (int ni = 0; ni < 4; ++ni) bv[ni] = bias[n0 + wcol + (ni << 4) + l15];
#pragma unroll
    for (int mi = 0; mi < 4; ++mi) {
        const int rbase = m0 + wrow + (mi << 4) + crow;
#pragma unroll
        for (int ni = 0; ni < 4; ++ni) {
            const int col = n0 + wcol + (ni << 4) + l15;
#pragma unroll
            for (int r = 0; r < 4; ++r) {
                float v = acc[mi][ni][r] + bv[ni];
                const size_t o = (size_t)(rbase + r) * D + col;
                if (mode == 0) {
                    outb[o] = f2bf(v > 0.0f ? v : 0.0f);
                } else if (mode == 1) {
                    hbuf[o] += v;
                } else {
                    outf[o] = hbuf[o] + v;
                }
            }
        }
    }
}

// per-row LayerNorm of h (in place) + bf16 copy into xb
__global__ __launch_bounds__(256) void resid_ln(float* __restrict__ h,
                                                unsigned short* __restrict__ xb,
                                                const float* __restrict__ gamma,
                                                const float* __restrict__ beta) {
    const int row = blockIdx.x;
    const int t = threadIdx.x;
    float* hr = h + (size_t)row * D;
    float4 v = ((float4*)hr)[t];
    float s = v.x + v.y + v.z + v.w;
    float s2 = v.x * v.x + v.y * v.y + v.z * v.z + v.w * v.w;
#pragma unroll
    for (int off = 32; off > 0; off >>= 1) {
        s += __shfl_down(s, off);
        s2 += __shfl_down(s2, off);
    }
    __shared__ float red[8];
    const int wid = t >> 6, lane = t & 63;
    if (lane == 0) { red[wid] = s; red[wid + 4] = s2; }
    __syncthreads();
    s = red[0] + red[1] + red[2] + red[3];
    s2 = red[4] + red[5] + red[6] + red[7];
    const float mu = s * (1.0f / D);
    const float var = s2 * (1.0f / D) - mu * mu;
    const float rs = rsqrtf(var + 1e-5f);
    float4 g = ((const float4*)gamma)[t];
    float4 b = ((const float4*)beta)[t];
    float4 o;
    o.x = (v.x - mu) * rs * g.x + b.x;
    o.y = (v.y - mu) * rs * g.y + b.y;
    o.z = (v.z - mu) * rs * g.z + b.z;
    o.w = (v.w - mu) * rs * g.w + b.w;
    ((float4*)hr)[t] = o;
    ushort4 u;
    u.x = f2bf(o.x); u.y = f2bf(o.y); u.z = f2bf(o.z); u.w = f2bf(o.w);
    ((ushort4*)(xb + (size_t)row * D))[t] = u;
}

extern "C" void kernel_launch(void* const* d_in, const int* in_sizes, int n_in,
                              void* d_out, int out_size, void* d_ws, size_t ws_size,
                              hipStream_t stream) {
    const float* x      = (const float*)d_in[0];
    const int*   q      = (const int*)d_in[1];
    const float* scales = (const float*)d_in[2];
    const float* biases = (const float*)d_in[3];
    const float* la     = (const float*)d_in[4];
    const float* lb     = (const float*)d_in[5];
    const float* lng    = (const float*)d_in[6];
    const float* lnb    = (const float*)d_in[7];
    float* out = (float*)d_out;

    char* p = (char*)d_ws;
    unsigned short* weff = (unsigned short*)p; p += (size_t)NLAYERS * D * D * 2;  // 37.75 MB
    unsigned short* xbA  = (unsigned short*)p; p += (size_t)BATCH * D * 2;        // 33.55 MB
    unsigned short* xbB  = (unsigned short*)p; p += (size_t)BATCH * D * 2;        // 33.55 MB
    float*          h    = (float*)p;                                             // 67.1 MB

    prep_weights<<<NLAYERS * D * 128 / 256, 256, 0, stream>>>(q, scales, la, lb, weff);
    init_h<<<BATCH * D / 4 / 256, 256, 0, stream>>>(x, h, xbA);

    dim3 ggrid(D / 128, BATCH / 128);
    for (int blk = 0; blk < 6; ++blk) {
        const int li = 3 * blk;
        gemm_fused<<<ggrid, 256, 0, stream>>>(xbA, weff + (size_t)li * D * D,
                                              biases + (size_t)li * D, xbB, nullptr, nullptr, 0);
        gemm_fused<<<ggrid, 256, 0, stream>>>(xbB, weff + (size_t)(li + 1) * D * D,
                                              biases + (size_t)(li + 1) * D, xbA, nullptr, nullptr, 0);
        gemm_fused<<<ggrid, 256, 0, stream>>>(xbA, weff + (size_t)(li + 2) * D * D,
                                              biases + (size_t)(li + 2) * D, nullptr, h, out,
                                              blk < 5 ? 1 : 2);
        if (blk < 5)
            resid_ln<<<BATCH, 256, 0, stream>>>(h, xbA, lng + (size_t)blk * D, lnb + (size_t)blk * D);
    }
}

// Round 2
// 1156.582 us; speedup vs baseline: 1.2896x; 1.2896x over previous
//
#include <hip/hip_runtime.h>
#include <cstdint>
#include <cstddef>

#define D 1024
#define BATCH 16384
#define NLAYERS 18
#define RR 32

typedef __attribute__((ext_vector_type(8))) __bf16 bf16x8;
typedef __attribute__((ext_vector_type(4))) float f32x4;
typedef __attribute__((address_space(3))) void lds_void_t;
typedef __attribute__((address_space(1))) void gmem_void_t;

__device__ __forceinline__ unsigned short f2bf(float f) {
    unsigned int b = __builtin_bit_cast(unsigned int, f);
    b += 0x7fffu + ((b >> 16) & 1u);
    return (unsigned short)(b >> 16);
}

// ---------------------------------------------------------------------------
// prep: W_eff[o][i] = (q/15*2-1)*scale + 4*sum_r lb[o][r]*la[r][i], bf16 out.
// Block = (layer, o-tile 64, i-tile 256). la/lb staged in LDS (fixes the
// L2 re-read storm: was 126us latency-bound at 0.7 TB/s).
// ---------------------------------------------------------------------------
__global__ __launch_bounds__(256) void prep_weights(
    const int* __restrict__ q, const float* __restrict__ scales,
    const float* __restrict__ la, const float* __restrict__ lb,
    unsigned short* __restrict__ weff) {
    __shared__ float la_s[32][260];
    __shared__ float lb_s[64][33];
    const int b = blockIdx.x;            // 18*16*4
    const int li = b >> 6;
    const int o0 = ((b >> 2) & 15) << 6;
    const int i0 = (b & 3) << 8;
    const int t = threadIdx.x;

    {   // lb tile: 64 rows x 32 r  (contiguous)
        const float* src = lb + ((size_t)li * D + o0) * RR;
        for (int i = t; i < 512; i += 256) {
            float4 v = ((const float4*)src)[i];
            const int o = i >> 3, c = (i & 7) << 2;
            lb_s[o][c] = v.x; lb_s[o][c + 1] = v.y; lb_s[o][c + 2] = v.z; lb_s[o][c + 3] = v.w;
        }
    }
    {   // la tile: 32 r x 256 cols
        for (int i = t; i < 2048; i += 256) {
            const int r = i >> 6, c = (i & 63) << 2;
            float4 v = *(const float4*)(la + ((size_t)li * RR + r) * D + i0 + c);
            la_s[r][c] = v.x; la_s[r][c + 1] = v.y; la_s[r][c + 2] = v.z; la_s[r][c + 3] = v.w;
        }
    }
    __syncthreads();

    for (int cidx = t; cidx < 2048; cidx += 256) {
        const int ol = cidx >> 5;
        const int i8 = (cidx & 31) << 3;
        float acc[8] = {0.f, 0.f, 0.f, 0.f, 0.f, 0.f, 0.f, 0.f};
#pragma unroll 8
        for (int r = 0; r < 32; ++r) {
            const float bv = lb_s[ol][r];
#pragma unroll
            for (int j = 0; j < 8; ++j) acc[j] += bv * la_s[r][i8 + j];
        }
        const size_t row = (size_t)li * D + o0 + ol;
        const int col = i0 + i8;
        const float s = scales[row * (D / 16) + (col >> 4)];
        const int* qp = q + row * D + col;
        int4 q0 = ((const int4*)qp)[0], q1 = ((const int4*)qp)[1];
        int qa[8] = {q0.x, q0.y, q0.z, q0.w, q1.x, q1.y, q1.z, q1.w};
        union { unsigned short us[8]; int4 v; } u;
        const float c = 2.0f / 15.0f;
#pragma unroll
        for (int j = 0; j < 8; ++j)
            u.us[j] = f2bf(((float)qa[j] * c - 1.0f) * s + 4.0f * acc[j]);
        *(int4*)(weff + row * D + col) = u.v;
    }
}

// h = x (f32); xb = bf16(x)
__global__ __launch_bounds__(256) void init_h(const float* __restrict__ x,
                                              float* __restrict__ h,
                                              unsigned short* __restrict__ xb) {
    const size_t i = (size_t)blockIdx.x * 256 + threadIdx.x;
    float4 v = ((const float4*)x)[i];
    ((float4*)h)[i] = v;
    ushort4 u;
    u.x = f2bf(v.x); u.y = f2bf(v.y); u.z = f2bf(v.z); u.w = f2bf(v.w);
    ((ushort4*)xb)[i] = u;
}

// ---------------------------------------------------------------------------
// 256x256 tile GEMM, 8 waves (2Mx4N), BK=32 half-steps, 4-slot LDS ring
// (4 x (A[256][32] + B[256][32]) bf16 = 128KB), depth-3 counted-vmcnt
// pipeline (T3+T4), raw s_barrier, setprio around MFMA cluster (T5).
// Swizzle for 64B rows: chunk16B ^= (row>>1)&3  -> 2-way conflicts (free).
// Linear LDS dest + pre-swizzled global source (global_load_lds rule).
// mode 0: outb = bf16(relu(v));  mode 1: hbuf += v;  mode 2: outf = hbuf + v.
// ---------------------------------------------------------------------------
#define BAR_PRE()  asm volatile("s_waitcnt vmcnt(12)" ::: "memory")
#define SBAR() do { asm volatile("" ::: "memory"); __builtin_amdgcn_s_barrier(); asm volatile("" ::: "memory"); } while (0)

__global__ __launch_bounds__(512, 2) void gemm256(
    const unsigned short* __restrict__ xb, const unsigned short* __restrict__ w,
    const float* __restrict__ bias,
    unsigned short* __restrict__ outb, float* __restrict__ hbuf,
    float* __restrict__ outf, int mode) {
    __shared__ __align__(16) char smem[131072];
    const int tid = threadIdx.x;
    const int wid = tid >> 6, lane = tid & 63;
    const int m0 = blockIdx.y << 8;
    const int n0 = blockIdx.x << 8;
    const int l15 = lane & 15, kgrp = lane >> 4;
    const int wrow = (wid >> 2) << 7;   // 0 / 128
    const int wcol = (wid & 3) << 6;    // 0..192

    f32x4 acc[8][4];
#pragma unroll
    for (int i = 0; i < 8; ++i)
#pragma unroll
        for (int j = 0; j < 4; ++j) acc[i][j] = 0.0f;

    // ---- stage half-step hs into slot hs&3 (4 global_load_lds / thread) ----
#define STAGE(hs)                                                              \
    do {                                                                       \
        const int slot_ = (hs) & 3;                                            \
        const int k0_ = (hs) << 5;                                             \
        char* sA_ = smem + slot_ * 32768;                                      \
        _Pragma("unroll")                                                      \
        for (int i_ = 0; i_ < 2; ++i_) {                                       \
            const int off_ = i_ * 8192 + (tid << 4);                           \
            const int r_ = off_ >> 6;                                          \
            const int j_ = ((off_ >> 4) & 3) ^ ((r_ >> 1) & 3);                \
            const unsigned short* ga_ = xb + (size_t)(m0 + r_) * D + k0_ + (j_ << 3); \
            const unsigned short* gb_ = w + (size_t)(n0 + r_) * D + k0_ + (j_ << 3);  \
            char* lA_ = sA_ + i_ * 8192 + (wid << 10);                         \
            __builtin_amdgcn_global_load_lds((const gmem_void_t*)ga_, (lds_void_t*)lA_, 16, 0, 0);          \
            __builtin_amdgcn_global_load_lds((const gmem_void_t*)gb_, (lds_void_t*)(lA_ + 16384), 16, 0, 0); \
        }                                                                      \
    } while (0)

#define COMPUTE(hs)                                                            \
    do {                                                                       \
        const char* sA_ = smem + ((hs) & 3) * 32768;                           \
        const char* sB_ = sA_ + 16384;                                         \
        bf16x8 a_[8], b_[4];                                                   \
        _Pragma("unroll")                                                      \
        for (int f_ = 0; f_ < 8; ++f_) {                                       \
            const int r_ = wrow + (f_ << 4) + l15;                             \
            a_[f_] = *(const bf16x8*)(sA_ + (r_ << 6) + ((kgrp ^ ((r_ >> 1) & 3)) << 4)); \
        }                                                                      \
        _Pragma("unroll")                                                      \
        for (int g_ = 0; g_ < 4; ++g_) {                                       \
            const int r_ = wcol + (g_ << 4) + l15;                             \
            b_[g_] = *(const bf16x8*)(sB_ + (r_ << 6) + ((kgrp ^ ((r_ >> 1) & 3)) << 4)); \
        }                                                                      \
        __builtin_amdgcn_s_setprio(1);                                         \
        _Pragma("unroll")                                                      \
        for (int mi_ = 0; mi_ < 8; ++mi_)                                      \
            _Pragma("unroll")                                                  \
            for (int ni_ = 0; ni_ < 4; ++ni_)                                  \
                acc[mi_][ni_] = __builtin_amdgcn_mfma_f32_16x16x32_bf16(       \
                    a_[mi_], b_[ni_], acc[mi_][ni_], 0, 0, 0);                 \
        __builtin_amdgcn_s_setprio(0);                                         \
    } while (0)

    STAGE(0); STAGE(1); STAGE(2);
    for (int h = 0; h < 29; ++h) {
        STAGE(h + 3);
        BAR_PRE();              // vmcnt(12): stage(h) landed, 3 in flight
        SBAR();
        COMPUTE(h);
        SBAR();                 // all reads of slot h done before overwrite
    }
    asm volatile("s_waitcnt vmcnt(8)" ::: "memory");
    SBAR(); COMPUTE(29); SBAR();
    asm volatile("s_waitcnt vmcnt(4)" ::: "memory");
    SBAR(); COMPUTE(30); SBAR();
    asm volatile("s_waitcnt vmcnt(0)" ::: "memory");
    SBAR(); COMPUTE(31);

    // epilogue: C/D layout col = lane&15, row = (lane>>4)*4 + r
    const int crow = kgrp << 2;
    float bv[4];
#pragma unroll
    for (int ni = 0; ni < 4; ++ni) bv[ni] = bias[n0 + wcol + (ni << 4) + l15];
#pragma unroll
    for (int mi = 0; mi < 8; ++mi) {
        const int rbase = m0 + wrow + (mi << 4) + crow;
#pragma unroll
        for (int ni = 0; ni < 4; ++ni) {
            const int col = n0 + wcol + (ni << 4) + l15;
#pragma unroll
            for (int r = 0; r < 4; ++r) {
                float v = acc[mi][ni][r] + bv[ni];
                const size_t o = (size_t)(rbase + r) * D + col;
                if (mode == 0) {
                    outb[o] = f2bf(v > 0.0f ? v : 0.0f);
                } else if (mode == 1) {
                    hbuf[o] += v;
                } else {
                    outf[o] = hbuf[o] + v;
                }
            }
        }
    }
}

// per-row LayerNorm of h (in place) + bf16 copy into xb
__global__ __launch_bounds__(256) void resid_ln(float* __restrict__ h,
                                                unsigned short* __restrict__ xb,
                                                const float* __restrict__ gamma,
                                                const float* __restrict__ beta) {
    const int row = blockIdx.x;
    const int t = threadIdx.x;
    float* hr = h + (size_t)row * D;
    float4 v = ((float4*)hr)[t];
    float s = v.x + v.y + v.z + v.w;
    float s2 = v.x * v.x + v.y * v.y + v.z * v.z + v.w * v.w;
#pragma unroll
    for (int off = 32; off > 0; off >>= 1) {
        s += __shfl_down(s, off);
        s2 += __shfl_down(s2, off);
    }
    __shared__ float red[8];
    const int wid = t >> 6, lane = t & 63;
    if (lane == 0) { red[wid] = s; red[wid + 4] = s2; }
    __syncthreads();
    s = red[0] + red[1] + red[2] + red[3];
    s2 = red[4] + red[5] + red[6] + red[7];
    const float mu = s * (1.0f / D);
    const float var = s2 * (1.0f / D) - mu * mu;
    const float rs = rsqrtf(var + 1e-5f);
    float4 g = ((const float4*)gamma)[t];
    float4 b = ((const float4*)beta)[t];
    float4 o;
    o.x = (v.x - mu) * rs * g.x + b.x;
    o.y = (v.y - mu) * rs * g.y + b.y;
    o.z = (v.z - mu) * rs * g.z + b.z;
    o.w = (v.w - mu) * rs * g.w + b.w;
    ((float4*)hr)[t] = o;
    ushort4 u;
    u.x = f2bf(o.x); u.y = f2bf(o.y); u.z = f2bf(o.z); u.w = f2bf(o.w);
    ((ushort4*)(xb + (size_t)row * D))[t] = u;
}

extern "C" void kernel_launch(void* const* d_in, const int* in_sizes, int n_in,
                              void* d_out, int out_size, void* d_ws, size_t ws_size,
                              hipStream_t stream) {
    const float* x      = (const float*)d_in[0];
    const int*   q      = (const int*)d_in[1];
    const float* scales = (const float*)d_in[2];
    const float* biases = (const float*)d_in[3];
    const float* la     = (const float*)d_in[4];
    const float* lb     = (const float*)d_in[5];
    const float* lng    = (const float*)d_in[6];
    const float* lnb    = (const float*)d_in[7];
    float* out = (float*)d_out;

    char* p = (char*)d_ws;
    unsigned short* weff = (unsigned short*)p; p += (size_t)NLAYERS * D * D * 2;
    unsigned short* xbA  = (unsigned short*)p; p += (size_t)BATCH * D * 2;
    unsigned short* xbB  = (unsigned short*)p; p += (size_t)BATCH * D * 2;
    float*          h    = (float*)p;

    prep_weights<<<NLAYERS * 16 * 4, 256, 0, stream>>>(q, scales, la, lb, weff);
    init_h<<<BATCH * D / 4 / 256, 256, 0, stream>>>(x, h, xbA);

    dim3 ggrid(D / 256, BATCH / 256);
    for (int blk = 0; blk < 6; ++blk) {
        const int li = 3 * blk;
        gemm256<<<ggrid, 512, 0, stream>>>(xbA, weff + (size_t)li * D * D,
                                           biases + (size_t)li * D, xbB, nullptr, nullptr, 0);
        gemm256<<<ggrid, 512, 0, stream>>>(xbB, weff + (size_t)(li + 1) * D * D,
                                           biases + (size_t)(li + 1) * D, xbA, nullptr, nullptr, 0);
        gemm256<<<ggrid, 512, 0, stream>>>(xbA, weff + (size_t)(li + 2) * D * D,
                                           biases + (size_t)(li + 2) * D, nullptr, h, out,
                                           blk < 5 ? 1 : 2);
        if (blk < 5)
            resid_ln<<<BATCH, 256, 0, stream>>>(h, xbA, lng + (size_t)blk * D, lnb + (size_t)blk * D);
    }
}

// Round 3
// 973.649 us; speedup vs baseline: 1.5319x; 1.1879x over previous
//
#include <hip/hip_runtime.h>
#include <cstdint>
#include <cstddef>

#define D 1024
#define BATCH 16384
#define NLAYERS 18
#define RR 32

typedef __attribute__((ext_vector_type(8))) __bf16 bf16x8;
typedef __attribute__((ext_vector_type(4))) float f32x4;
typedef __attribute__((address_space(3))) void lds_void_t;
typedef __attribute__((address_space(1))) void gmem_void_t;

__device__ __forceinline__ unsigned short f2bf(float f) {
    unsigned int b = __builtin_bit_cast(unsigned int, f);
    b += 0x7fffu + ((b >> 16) & 1u);
    return (unsigned short)(b >> 16);
}
__device__ __forceinline__ float bf2f(unsigned short u) {
    return __builtin_bit_cast(float, (unsigned int)u << 16);
}

// ---------------------------------------------------------------------------
// prep: W_eff[o][i] = (q/15*2-1)*scale + 4*sum_r lb[o][r]*la[r][i], bf16 out.
// Block = (layer, o-tile 64, i-tile 256). la/lb staged in LDS.
// ---------------------------------------------------------------------------
__global__ __launch_bounds__(256) void prep_weights(
    const int* __restrict__ q, const float* __restrict__ scales,
    const float* __restrict__ la, const float* __restrict__ lb,
    unsigned short* __restrict__ weff) {
    __shared__ float la_s[32][260];
    __shared__ float lb_s[64][33];
    const int b = blockIdx.x;            // 18*16*4
    const int li = b >> 6;
    const int o0 = ((b >> 2) & 15) << 6;
    const int i0 = (b & 3) << 8;
    const int t = threadIdx.x;

    {   // lb tile: 64 rows x 32 r
        const float* src = lb + ((size_t)li * D + o0) * RR;
        for (int i = t; i < 512; i += 256) {
            float4 v = ((const float4*)src)[i];
            const int o = i >> 3, c = (i & 7) << 2;
            lb_s[o][c] = v.x; lb_s[o][c + 1] = v.y; lb_s[o][c + 2] = v.z; lb_s[o][c + 3] = v.w;
        }
    }
    {   // la tile: 32 r x 256 cols
        for (int i = t; i < 2048; i += 256) {
            const int r = i >> 6, c = (i & 63) << 2;
            float4 v = *(const float4*)(la + ((size_t)li * RR + r) * D + i0 + c);
            la_s[r][c] = v.x; la_s[r][c + 1] = v.y; la_s[r][c + 2] = v.z; la_s[r][c + 3] = v.w;
        }
    }
    __syncthreads();

    for (int cidx = t; cidx < 2048; cidx += 256) {
        const int ol = cidx >> 5;
        const int i8 = (cidx & 31) << 3;
        float acc[8] = {0.f, 0.f, 0.f, 0.f, 0.f, 0.f, 0.f, 0.f};
#pragma unroll 8
        for (int r = 0; r < 32; ++r) {
            const float bv = lb_s[ol][r];
#pragma unroll
            for (int j = 0; j < 8; ++j) acc[j] += bv * la_s[r][i8 + j];
        }
        const size_t row = (size_t)li * D + o0 + ol;
        const int col = i0 + i8;
        const float s = scales[row * (D / 16) + (col >> 4)];
        const int* qp = q + row * D + col;
        int4 q0 = ((const int4*)qp)[0], q1 = ((const int4*)qp)[1];
        int qa[8] = {q0.x, q0.y, q0.z, q0.w, q1.x, q1.y, q1.z, q1.w};
        union { unsigned short us[8]; int4 v; } u;
        const float c = 2.0f / 15.0f;
#pragma unroll
        for (int j = 0; j < 8; ++j)
            u.us[j] = f2bf(((float)qa[j] * c - 1.0f) * s + 4.0f * acc[j]);
        *(int4*)(weff + row * D + col) = u.v;
    }
}

// h = x (f32); xb = bf16(x)
__global__ __launch_bounds__(256) void init_h(const float* __restrict__ x,
                                              float* __restrict__ h,
                                              unsigned short* __restrict__ xb) {
    const size_t i = (size_t)blockIdx.x * 256 + threadIdx.x;
    float4 v = ((const float4*)x)[i];
    ((float4*)h)[i] = v;
    ushort4 u;
    u.x = f2bf(v.x); u.y = f2bf(v.y); u.z = f2bf(v.z); u.w = f2bf(v.w);
    ((ushort4*)xb)[i] = u;
}

// ---------------------------------------------------------------------------
// 256x256 tile GEMM, 8 waves (2Mx4N), BK=32 half-steps, 4-slot LDS ring,
// depth-3 counted-vmcnt pipeline, raw s_barrier, setprio around MFMA.
// mode 0: outb = bf16(relu(v));  mode 1: outb = bf16(v).
// ---------------------------------------------------------------------------
#define BAR_PRE()  asm volatile("s_waitcnt vmcnt(12)" ::: "memory")
#define SBAR() do { asm volatile("" ::: "memory"); __builtin_amdgcn_s_barrier(); asm volatile("" ::: "memory"); } while (0)

__global__ __launch_bounds__(512, 2) void gemm256(
    const unsigned short* __restrict__ xb, const unsigned short* __restrict__ w,
    const float* __restrict__ bias,
    unsigned short* __restrict__ outb, int mode) {
    __shared__ __align__(16) char smem[131072];
    const int tid = threadIdx.x;
    const int wid = tid >> 6, lane = tid & 63;
    const int m0 = blockIdx.y << 8;
    const int n0 = blockIdx.x << 8;
    const int l15 = lane & 15, kgrp = lane >> 4;
    const int wrow = (wid >> 2) << 7;   // 0 / 128
    const int wcol = (wid & 3) << 6;    // 0..192

    f32x4 acc[8][4];
#pragma unroll
    for (int i = 0; i < 8; ++i)
#pragma unroll
        for (int j = 0; j < 4; ++j) acc[i][j] = 0.0f;

#define STAGE(hs)                                                              \
    do {                                                                       \
        const int slot_ = (hs) & 3;                                            \
        const int k0_ = (hs) << 5;                                             \
        char* sA_ = smem + slot_ * 32768;                                      \
        _Pragma("unroll")                                                      \
        for (int i_ = 0; i_ < 2; ++i_) {                                       \
            const int off_ = i_ * 8192 + (tid << 4);                           \
            const int r_ = off_ >> 6;                                          \
            const int j_ = ((off_ >> 4) & 3) ^ ((r_ >> 1) & 3);                \
            const unsigned short* ga_ = xb + (size_t)(m0 + r_) * D + k0_ + (j_ << 3); \
            const unsigned short* gb_ = w + (size_t)(n0 + r_) * D + k0_ + (j_ << 3);  \
            char* lA_ = sA_ + i_ * 8192 + (wid << 10);                         \
            __builtin_amdgcn_global_load_lds((const gmem_void_t*)ga_, (lds_void_t*)lA_, 16, 0, 0);          \
            __builtin_amdgcn_global_load_lds((const gmem_void_t*)gb_, (lds_void_t*)(lA_ + 16384), 16, 0, 0); \
        }                                                                      \
    } while (0)

#define COMPUTE(hs)                                                            \
    do {                                                                       \
        const char* sA_ = smem + ((hs) & 3) * 32768;                           \
        const char* sB_ = sA_ + 16384;                                         \
        bf16x8 a_[8], b_[4];                                                   \
        _Pragma("unroll")                                                      \
        for (int f_ = 0; f_ < 8; ++f_) {                                       \
            const int r_ = wrow + (f_ << 4) + l15;                             \
            a_[f_] = *(const bf16x8*)(sA_ + (r_ << 6) + ((kgrp ^ ((r_ >> 1) & 3)) << 4)); \
        }                                                                      \
        _Pragma("unroll")                                                      \
        for (int g_ = 0; g_ < 4; ++g_) {                                       \
            const int r_ = wcol + (g_ << 4) + l15;                             \
            b_[g_] = *(const bf16x8*)(sB_ + (r_ << 6) + ((kgrp ^ ((r_ >> 1) & 3)) << 4)); \
        }                                                                      \
        __builtin_amdgcn_s_setprio(1);                                         \
        _Pragma("unroll")                                                      \
        for (int mi_ = 0; mi_ < 8; ++mi_)                                      \
            _Pragma("unroll")                                                  \
            for (int ni_ = 0; ni_ < 4; ++ni_)                                  \
                acc[mi_][ni_] = __builtin_amdgcn_mfma_f32_16x16x32_bf16(       \
                    a_[mi_], b_[ni_], acc[mi_][ni_], 0, 0, 0);                 \
        __builtin_amdgcn_s_setprio(0);                                         \
    } while (0)

    STAGE(0); STAGE(1); STAGE(2);
    for (int h = 0; h < 29; ++h) {
        STAGE(h + 3);
        BAR_PRE();              // vmcnt(12): stage(h) landed, 3 in flight
        SBAR();
        COMPUTE(h);
        SBAR();                 // all reads of slot h done before overwrite
    }
    asm volatile("s_waitcnt vmcnt(8)" ::: "memory");
    SBAR(); COMPUTE(29); SBAR();
    asm volatile("s_waitcnt vmcnt(4)" ::: "memory");
    SBAR(); COMPUTE(30); SBAR();
    asm volatile("s_waitcnt vmcnt(0)" ::: "memory");
    SBAR(); COMPUTE(31);

    // epilogue: C/D layout col = lane&15, row = (lane>>4)*4 + r
    const int crow = kgrp << 2;
    float bv[4];
#pragma unroll
    for (int ni = 0; ni < 4; ++ni) bv[ni] = bias[n0 + wcol + (ni << 4) + l15];
#pragma unroll
    for (int mi = 0; mi < 8; ++mi) {
        const int rbase = m0 + wrow + (mi << 4) + crow;
#pragma unroll
        for (int ni = 0; ni < 4; ++ni) {
            const int col = n0 + wcol + (ni << 4) + l15;
#pragma unroll
            for (int r = 0; r < 4; ++r) {
                float v = acc[mi][ni][r] + bv[ni];
                if (mode == 0) v = v > 0.0f ? v : 0.0f;
                outb[(size_t)(rbase + r) * D + col] = f2bf(v);
            }
        }
    }
}

// h = LN(h + v) in place; xb = bf16(result)
__global__ __launch_bounds__(256) void resid_ln_v(
    float* __restrict__ h, const unsigned short* __restrict__ vb,
    unsigned short* __restrict__ xb,
    const float* __restrict__ gamma, const float* __restrict__ beta) {
    const int row = blockIdx.x;
    const int t = threadIdx.x;
    float* hr = h + (size_t)row * D;
    float4 v = ((float4*)hr)[t];
    ushort4 vv = ((const ushort4*)(vb + (size_t)row * D))[t];
    v.x += bf2f(vv.x); v.y += bf2f(vv.y); v.z += bf2f(vv.z); v.w += bf2f(vv.w);
    float s = v.x + v.y + v.z + v.w;
    float s2 = v.x * v.x + v.y * v.y + v.z * v.z + v.w * v.w;
#pragma unroll
    for (int off = 32; off > 0; off >>= 1) {
        s += __shfl_down(s, off);
        s2 += __shfl_down(s2, off);
    }
    __shared__ float red[8];
    const int wid = t >> 6, lane = t & 63;
    if (lane == 0) { red[wid] = s; red[wid + 4] = s2; }
    __syncthreads();
    s = red[0] + red[1] + red[2] + red[3];
    s2 = red[4] + red[5] + red[6] + red[7];
    const float mu = s * (1.0f / D);
    const float var = s2 * (1.0f / D) - mu * mu;
    const float rs = rsqrtf(var + 1e-5f);
    float4 g = ((const float4*)gamma)[t];
    float4 b = ((const float4*)beta)[t];
    float4 o;
    o.x = (v.x - mu) * rs * g.x + b.x;
    o.y = (v.y - mu) * rs * g.y + b.y;
    o.z = (v.z - mu) * rs * g.z + b.z;
    o.w = (v.w - mu) * rs * g.w + b.w;
    ((float4*)hr)[t] = o;
    ushort4 u;
    u.x = f2bf(o.x); u.y = f2bf(o.y); u.z = f2bf(o.z); u.w = f2bf(o.w);
    ((ushort4*)(xb + (size_t)row * D))[t] = u;
}

// out = h + v  (final block, no LN)
__global__ __launch_bounds__(256) void final_add(
    const float* __restrict__ h, const unsigned short* __restrict__ vb,
    float* __restrict__ out) {
    const size_t i = (size_t)blockIdx.x * 256 + threadIdx.x;
    float4 hv = ((const float4*)h)[i];
    ushort4 vv = ((const ushort4*)vb)[i];
    float4 o;
    o.x = hv.x + bf2f(vv.x); o.y = hv.y + bf2f(vv.y);
    o.z = hv.z + bf2f(vv.z); o.w = hv.w + bf2f(vv.w);
    ((float4*)out)[i] = o;
}

extern "C" void kernel_launch(void* const* d_in, const int* in_sizes, int n_in,
                              void* d_out, int out_size, void* d_ws, size_t ws_size,
                              hipStream_t stream) {
    const float* x      = (const float*)d_in[0];
    const int*   q      = (const int*)d_in[1];
    const float* scales = (const float*)d_in[2];
    const float* biases = (const float*)d_in[3];
    const float* la     = (const float*)d_in[4];
    const float* lb     = (const float*)d_in[5];
    const float* lng    = (const float*)d_in[6];
    const float* lnb    = (const float*)d_in[7];
    float* out = (float*)d_out;

    char* p = (char*)d_ws;
    unsigned short* weff = (unsigned short*)p; p += (size_t)NLAYERS * D * D * 2;
    unsigned short* xbA  = (unsigned short*)p; p += (size_t)BATCH * D * 2;
    unsigned short* xbB  = (unsigned short*)p; p += (size_t)BATCH * D * 2;
    float*          h    = (float*)p;

    prep_weights<<<NLAYERS * 16 * 4, 256, 0, stream>>>(q, scales, la, lb, weff);
    init_h<<<BATCH * D / 4 / 256, 256, 0, stream>>>(x, h, xbA);

    dim3 ggrid(D / 256, BATCH / 256);
    for (int blk = 0; blk < 6; ++blk) {
        const int li = 3 * blk;
        gemm256<<<ggrid, 512, 0, stream>>>(xbA, weff + (size_t)li * D * D,
                                           biases + (size_t)li * D, xbB, 0);
        gemm256<<<ggrid, 512, 0, stream>>>(xbB, weff + (size_t)(li + 1) * D * D,
                                           biases + (size_t)(li + 1) * D, xbA, 0);
        gemm256<<<ggrid, 512, 0, stream>>>(xbA, weff + (size_t)(li + 2) * D * D,
                                           biases + (size_t)(li + 2) * D, xbB, 1);
        if (blk < 5)
            resid_ln_v<<<BATCH, 256, 0, stream>>>(h, xbB, xbA,
                                                  lng + (size_t)blk * D, lnb + (size_t)blk * D);
        else
            final_add<<<BATCH * D / 4 / 256, 256, 0, stream>>>(h, xbB, out);
    }
}

// Round 4
// 940.193 us; speedup vs baseline: 1.5864x; 1.0356x over previous
//
#include <hip/hip_runtime.h>
#include <cstdint>
#include <cstddef>

#define D 1024
#define BATCH 16384
#define NLAYERS 18
#define RR 32

typedef __attribute__((ext_vector_type(8))) __bf16 bf16x8;
typedef __attribute__((ext_vector_type(4))) float f32x4;
typedef __attribute__((address_space(3))) void lds_void_t;
typedef __attribute__((address_space(1))) void gmem_void_t;

__device__ __forceinline__ unsigned short f2bf(float f) {
    unsigned int b = __builtin_bit_cast(unsigned int, f);
    b += 0x7fffu + ((b >> 16) & 1u);
    return (unsigned short)(b >> 16);
}
__device__ __forceinline__ float bf2f(unsigned short u) {
    return __builtin_bit_cast(float, (unsigned int)u << 16);
}

// ---------------------------------------------------------------------------
// prep: W_eff[o][i] = (q/15*2-1)*scale + 4*sum_r lb[o][r]*la[r][i], bf16 out.
// Mapping: ol = lane (lb_s stride-33 conflict-free), la_s reads wave-uniform
// broadcast (free). Output staged in out_s (odd 16B-slot rows -> conflict-
// free b128) then coalesced global writeback. R2 had 9.4M bank conflicts
// from lane-stride-8 la_s reads.
// ---------------------------------------------------------------------------
__global__ __launch_bounds__(256) void prep_weights(
    const int* __restrict__ q, const float* __restrict__ scales,
    const float* __restrict__ la, const float* __restrict__ lb,
    unsigned short* __restrict__ weff) {
    __shared__ float la_s[32][260];
    __shared__ float lb_s[64][33];
    __shared__ unsigned short out_s[64][264];   // 528B rows = 33 16B-slots (odd)
    const int b = blockIdx.x;            // 18*16*4
    const int li = b >> 6;
    const int o0 = ((b >> 2) & 15) << 6;
    const int i0 = (b & 3) << 8;
    const int t = threadIdx.x;

    {   // lb tile: 64 rows x 32 r
        const float* src = lb + ((size_t)li * D + o0) * RR;
        for (int i = t; i < 512; i += 256) {
            float4 v = ((const float4*)src)[i];
            const int o = i >> 3, c = (i & 7) << 2;
            lb_s[o][c] = v.x; lb_s[o][c + 1] = v.y; lb_s[o][c + 2] = v.z; lb_s[o][c + 3] = v.w;
        }
    }
    {   // la tile: 32 r x 256 cols
        for (int i = t; i < 2048; i += 256) {
            const int r = i >> 6, c = (i & 63) << 2;
            float4 v = *(const float4*)(la + ((size_t)li * RR + r) * D + i0 + c);
            la_s[r][c] = v.x; la_s[r][c + 1] = v.y; la_s[r][c + 2] = v.z; la_s[r][c + 3] = v.w;
        }
    }
    __syncthreads();

    const int ol = t & 63;               // lane -> output row (stride-33 lb reads)
    const int ibase = (t >> 6) << 6;     // wave -> 64-col stripe (broadcast la)
    const size_t grow = (size_t)li * D + o0 + ol;
    float lbr[32];
#pragma unroll
    for (int r = 0; r < 32; ++r) lbr[r] = lb_s[ol][r];

#pragma unroll 1
    for (int iter = 0; iter < 8; ++iter) {
        const int i8 = ibase + (iter << 3);
        const int col = i0 + i8;
        // issue global loads early (cover latency under the FMA chain)
        const float s = scales[grow * (D / 16) + (col >> 4)];
        const int* qp = q + grow * D + col;
        int4 q0 = ((const int4*)qp)[0], q1 = ((const int4*)qp)[1];

        float acc[8] = {0.f, 0.f, 0.f, 0.f, 0.f, 0.f, 0.f, 0.f};
#pragma unroll 16
        for (int r = 0; r < 32; ++r) {
            float4 u0 = *(const float4*)&la_s[r][i8];       // wave-uniform: broadcast
            float4 u1 = *(const float4*)&la_s[r][i8 + 4];
            const float bv = lbr[r];
            acc[0] += bv * u0.x; acc[1] += bv * u0.y; acc[2] += bv * u0.z; acc[3] += bv * u0.w;
            acc[4] += bv * u1.x; acc[5] += bv * u1.y; acc[6] += bv * u1.z; acc[7] += bv * u1.w;
        }
        int qa[8] = {q0.x, q0.y, q0.z, q0.w, q1.x, q1.y, q1.z, q1.w};
        union { unsigned short us[8]; int4 v; } u;
        const float c = 2.0f / 15.0f;
#pragma unroll
        for (int j = 0; j < 8; ++j)
            u.us[j] = f2bf(((float)qa[j] * c - 1.0f) * s + 4.0f * acc[j]);
        *(int4*)&out_s[ol][i8] = u.v;
    }
    __syncthreads();

    // coalesced writeback: thread t -> row t>>2, 64-col group (t&3)
    const int row = t >> 2, cg = (t & 3) << 6;
    const size_t gbase = ((size_t)li * D + o0 + row) * D + i0 + cg;
#pragma unroll
    for (int j = 0; j < 8; ++j)
        *(int4*)(weff + gbase + (j << 3)) = *(const int4*)&out_s[row][cg + (j << 3)];
}

// h = x (f32); xb = bf16(x)
__global__ __launch_bounds__(256) void init_h(const float* __restrict__ x,
                                              float* __restrict__ h,
                                              unsigned short* __restrict__ xb) {
    const size_t i = (size_t)blockIdx.x * 256 + threadIdx.x;
    float4 v = ((const float4*)x)[i];
    ((float4*)h)[i] = v;
    ushort4 u;
    u.x = f2bf(v.x); u.y = f2bf(v.y); u.z = f2bf(v.z); u.w = f2bf(v.w);
    ((ushort4*)xb)[i] = u;
}

// ---------------------------------------------------------------------------
// 256x256 tile GEMM, 8 waves (2Mx4N), BK=32 half-steps, 4-slot LDS ring,
// depth-3 counted-vmcnt pipeline. m201-style phase split: 2 phases of
// 16 MFMA per half-step, ds_read/stage interleaved, vmcnt(8) once per
// half-step (never 0 in main loop). T5 setprio, T1 XCD-chunked swizzle.
// mode 0: outb = bf16(relu(v));  mode 1: outb = bf16(v).
// ---------------------------------------------------------------------------
#define SBAR() do { asm volatile("" ::: "memory"); __builtin_amdgcn_s_barrier(); asm volatile("" ::: "memory"); } while (0)

__global__ __launch_bounds__(512, 2) void gemm256(
    const unsigned short* __restrict__ xb, const unsigned short* __restrict__ w,
    const float* __restrict__ bias,
    unsigned short* __restrict__ outb, int mode) {
    __shared__ __align__(16) char smem[131072];
    const int tid = threadIdx.x;
    const int wid = tid >> 6, lane = tid & 63;
    // XCD-chunked swizzle: grid is 4x64 = 256 blocks = 1/CU; XCD k gets
    // y in [8k, 8k+8) so its xb panels (4MB) stay in its private L2.
    const int bid = blockIdx.x + (blockIdx.y << 2);
    const int xcd = bid & 7, slot = bid >> 3;
    const int m0 = ((xcd << 3) + (slot >> 2)) << 8;
    const int n0 = (slot & 3) << 8;
    const int l15 = lane & 15, kgrp = lane >> 4;
    const int wrow = (wid >> 2) << 7;   // 0 / 128
    const int wcol = (wid & 3) << 6;    // 0..192

    f32x4 acc[8][4];
#pragma unroll
    for (int i = 0; i < 8; ++i)
#pragma unroll
        for (int j = 0; j < 4; ++j) acc[i][j] = 0.0f;

    // 2 global_load_lds for half hs, quarter i_ (rows 0-127 / 128-255)
#define STAGE_HALF(hs, i_)                                                     \
    do {                                                                       \
        const int k0_ = (hs) << 5;                                             \
        char* sA_ = smem + ((hs) & 3) * 32768;                                 \
        const int off_ = (i_) * 8192 + (tid << 4);                             \
        const int r_ = off_ >> 6;                                              \
        const int j_ = ((off_ >> 4) & 3) ^ ((r_ >> 1) & 3);                    \
        const unsigned short* ga_ = xb + (size_t)(m0 + r_) * D + k0_ + (j_ << 3); \
        const unsigned short* gb_ = w + (size_t)(n0 + r_) * D + k0_ + (j_ << 3);  \
        char* lA_ = sA_ + (i_) * 8192 + (wid << 10);                           \
        __builtin_amdgcn_global_load_lds((const gmem_void_t*)ga_, (lds_void_t*)lA_, 16, 0, 0);          \
        __builtin_amdgcn_global_load_lds((const gmem_void_t*)gb_, (lds_void_t*)(lA_ + 16384), 16, 0, 0); \
    } while (0)

    STAGE_HALF(0, 0); STAGE_HALF(0, 1);
    STAGE_HALF(1, 0); STAGE_HALF(1, 1);
    STAGE_HALF(2, 0); STAGE_HALF(2, 1);
    asm volatile("s_waitcnt vmcnt(8)" ::: "memory");   // slot 0 landed
    SBAR();

    for (int h = 0; h < 32; ++h) {
        const char* sA = smem + (h & 3) * 32768;
        const char* sB = sA + 16384;
        bf16x8 a[8], b[4];
        // ---- phase A: a0-3 + b0-3 reads, 2 stage loads, 16 MFMA ----
#pragma unroll
        for (int f = 0; f < 4; ++f) {
            const int r = wrow + (f << 4) + l15;
            a[f] = *(const bf16x8*)(sA + (r << 6) + ((kgrp ^ ((r >> 1) & 3)) << 4));
        }
#pragma unroll
        for (int g = 0; g < 4; ++g) {
            const int r = wcol + (g << 4) + l15;
            b[g] = *(const bf16x8*)(sB + (r << 6) + ((kgrp ^ ((r >> 1) & 3)) << 4));
        }
        if (h < 29) STAGE_HALF(h + 3, 0);
        SBAR();
        asm volatile("s_waitcnt lgkmcnt(0)" ::: "memory");
        __builtin_amdgcn_s_setprio(1);
#pragma unroll
        for (int mi = 0; mi < 4; ++mi)
#pragma unroll
            for (int ni = 0; ni < 4; ++ni)
                acc[mi][ni] = __builtin_amdgcn_mfma_f32_16x16x32_bf16(
                    a[mi], b[ni], acc[mi][ni], 0, 0, 0);
        __builtin_amdgcn_s_setprio(0);
        SBAR();
        // ---- phase B: a4-7 reads, 2 stage loads, vmcnt, 16 MFMA ----
#pragma unroll
        for (int f = 4; f < 8; ++f) {
            const int r = wrow + (f << 4) + l15;
            a[f] = *(const bf16x8*)(sA + (r << 6) + ((kgrp ^ ((r >> 1) & 3)) << 4));
        }
        if (h < 29) {
            STAGE_HALF(h + 3, 1);
            asm volatile("s_waitcnt vmcnt(8)" ::: "memory");  // stage h+1 landed
        } else if (h == 29) {
            asm volatile("s_waitcnt vmcnt(4)" ::: "memory");
        } else if (h == 30) {
            asm volatile("s_waitcnt vmcnt(0)" ::: "memory");
        }
        SBAR();
        asm volatile("s_waitcnt lgkmcnt(0)" ::: "memory");
        __builtin_amdgcn_s_setprio(1);
#pragma unroll
        for (int mi = 4; mi < 8; ++mi)
#pragma unroll
            for (int ni = 0; ni < 4; ++ni)
                acc[mi][ni] = __builtin_amdgcn_mfma_f32_16x16x32_bf16(
                    a[mi], b[ni], acc[mi][ni], 0, 0, 0);
        __builtin_amdgcn_s_setprio(0);
        SBAR();
    }

    // epilogue: C/D layout col = lane&15, row = (lane>>4)*4 + r
    const int crow = kgrp << 2;
    float bv[4];
#pragma unroll
    for (int ni = 0; ni < 4; ++ni) bv[ni] = bias[n0 + wcol + (ni << 4) + l15];
#pragma unroll
    for (int mi = 0; mi < 8; ++mi) {
        const int rbase = m0 + wrow + (mi << 4) + crow;
#pragma unroll
        for (int ni = 0; ni < 4; ++ni) {
            const int col = n0 + wcol + (ni << 4) + l15;
#pragma unroll
            for (int r = 0; r < 4; ++r) {
                float v = acc[mi][ni][r] + bv[ni];
                if (mode == 0) v = v > 0.0f ? v : 0.0f;
                outb[(size_t)(rbase + r) * D + col] = f2bf(v);
            }
        }
    }
}

// h = LN(h + v) in place; xb = bf16(result)
__global__ __launch_bounds__(256) void resid_ln_v(
    float* __restrict__ h, const unsigned short* __restrict__ vb,
    unsigned short* __restrict__ xb,
    const float* __restrict__ gamma, const float* __restrict__ beta) {
    const int row = blockIdx.x;
    const int t = threadIdx.x;
    float* hr = h + (size_t)row * D;
    float4 v = ((float4*)hr)[t];
    ushort4 vv = ((const ushort4*)(vb + (size_t)row * D))[t];
    v.x += bf2f(vv.x); v.y += bf2f(vv.y); v.z += bf2f(vv.z); v.w += bf2f(vv.w);
    float s = v.x + v.y + v.z + v.w;
    float s2 = v.x * v.x + v.y * v.y + v.z * v.z + v.w * v.w;
#pragma unroll
    for (int off = 32; off > 0; off >>= 1) {
        s += __shfl_down(s, off);
        s2 += __shfl_down(s2, off);
    }
    __shared__ float red[8];
    const int wid = t >> 6, lane = t & 63;
    if (lane == 0) { red[wid] = s; red[wid + 4] = s2; }
    __syncthreads();
    s = red[0] + red[1] + red[2] + red[3];
    s2 = red[4] + red[5] + red[6] + red[7];
    const float mu = s * (1.0f / D);
    const float var = s2 * (1.0f / D) - mu * mu;
    const float rs = rsqrtf(var + 1e-5f);
    float4 g = ((const float4*)gamma)[t];
    float4 b = ((const float4*)beta)[t];
    float4 o;
    o.x = (v.x - mu) * rs * g.x + b.x;
    o.y = (v.y - mu) * rs * g.y + b.y;
    o.z = (v.z - mu) * rs * g.z + b.z;
    o.w = (v.w - mu) * rs * g.w + b.w;
    ((float4*)hr)[t] = o;
    ushort4 u;
    u.x = f2bf(o.x); u.y = f2bf(o.y); u.z = f2bf(o.z); u.w = f2bf(o.w);
    ((ushort4*)(xb + (size_t)row * D))[t] = u;
}

// out = h + v  (final block, no LN)
__global__ __launch_bounds__(256) void final_add(
    const float* __restrict__ h, const unsigned short* __restrict__ vb,
    float* __restrict__ out) {
    const size_t i = (size_t)blockIdx.x * 256 + threadIdx.x;
    float4 hv = ((const float4*)h)[i];
    ushort4 vv = ((const ushort4*)vb)[i];
    float4 o;
    o.x = hv.x + bf2f(vv.x); o.y = hv.y + bf2f(vv.y);
    o.z = hv.z + bf2f(vv.z); o.w = hv.w + bf2f(vv.w);
    ((float4*)out)[i] = o;
}

extern "C" void kernel_launch(void* const* d_in, const int* in_sizes, int n_in,
                              void* d_out, int out_size, void* d_ws, size_t ws_size,
                              hipStream_t stream) {
    const float* x      = (const float*)d_in[0];
    const int*   q      = (const int*)d_in[1];
    const float* scales = (const float*)d_in[2];
    const float* biases = (const float*)d_in[3];
    const float* la     = (const float*)d_in[4];
    const float* lb     = (const float*)d_in[5];
    const float* lng    = (const float*)d_in[6];
    const float* lnb    = (const float*)d_in[7];
    float* out = (float*)d_out;

    char* p = (char*)d_ws;
    unsigned short* weff = (unsigned short*)p; p += (size_t)NLAYERS * D * D * 2;
    unsigned short* xbA  = (unsigned short*)p; p += (size_t)BATCH * D * 2;
    unsigned short* xbB  = (unsigned short*)p; p += (size_t)BATCH * D * 2;
    float*          h    = (float*)p;

    prep_weights<<<NLAYERS * 16 * 4, 256, 0, stream>>>(q, scales, la, lb, weff);
    init_h<<<BATCH * D / 4 / 256, 256, 0, stream>>>(x, h, xbA);

    dim3 ggrid(D / 256, BATCH / 256);
    for (int blk = 0; blk < 6; ++blk) {
        const int li = 3 * blk;
        gemm256<<<ggrid, 512, 0, stream>>>(xbA, weff + (size_t)li * D * D,
                                           biases + (size_t)li * D, xbB, 0);
        gemm256<<<ggrid, 512, 0, stream>>>(xbB, weff + (size_t)(li + 1) * D * D,
                                           biases + (size_t)(li + 1) * D, xbA, 0);
        gemm256<<<ggrid, 512, 0, stream>>>(xbA, weff + (size_t)(li + 2) * D * D,
                                           biases + (size_t)(li + 2) * D, xbB, 1);
        if (blk < 5)
            resid_ln_v<<<BATCH, 256, 0, stream>>>(h, xbB, xbA,
                                                  lng + (size_t)blk * D, lnb + (size_t)blk * D);
        else
            final_add<<<BATCH * D / 4 / 256, 256, 0, stream>>>(h, xbB, out);
    }
}